// Round 7
// baseline (751.053 us; speedup 1.0000x reference)
//
#include <hip/hip_runtime.h>
#include <math.h>

#define TPB  256
#define NPGC 64
#define EPGC 128
#define K1C  52
#define K2C  42
#define F0   30
#define F1   50
#define F2   100

// ---------------- graph kernel ----------------
// LDS 31.9KB -> 5 blocks/CU.
// Region A (20800B): h1[64][50] + xa[64][30]@float-ofs3200 (conv1)  ->  h2[52][100] (conv2+)
// Region B (10400B): xs[64][30] -> ha[52][50] -> rd[400]
// GCN computed aggregation-first: h = relu((N.x) @ W + b)  ==  relu(N.(x@W) + b)
struct GS {
    float A[5200] __attribute__((aligned(16)));
    float B[2600] __attribute__((aligned(16)));
    float dinv[NPGC];
    float score[NPGC];
    float score2[K1C];
    unsigned short off[NPGC + 1];
    unsigned char rowm[EPGC];
    unsigned char colm[EPGC];
    unsigned char erow[EPGC];   // CSR1: original src node; CSR2: mapped src (pooled idx)
    unsigned char inv[NPGC];
    unsigned char inv2[K2C + 2];
    signed char   map[NPGC];
};

__global__ __launch_bounds__(TPB, 5)
void molgen_graph(const float* __restrict__ x,
                  const int* __restrict__ ei,
                  const float* __restrict__ w1,  const float* __restrict__ b1,
                  const float* __restrict__ pw1,
                  const float* __restrict__ w2,  const float* __restrict__ cb2,
                  const float* __restrict__ pw2,
                  float* __restrict__ ws_pooled,
                  int E)
{
    __shared__ GS s;
    const int g = blockIdx.x;
    const int t = threadIdx.x;

    float* const h1 = s.A;            // [64][50]
    float* const xa = s.A + 3200;     // [64][30]
    float* const h2 = s.A;            // [52][100]
    float* const xs = s.B;            // [64][30]
    float* const ha = s.B;            // [52][50]
    float* const rd = s.B;            // [400] readout partials

    // P0: edges (u8 local ids) + stage x (float4)
    if (t < EPGC) {
        s.rowm[t] = (unsigned char)(ei[(size_t)g * EPGC + t] - g * NPGC);
        s.colm[t] = (unsigned char)(ei[(size_t)E + (size_t)g * EPGC + t] - g * NPGC);
    }
    {
        const float4* xsrc = (const float4*)(x + (size_t)g * (NPGC * F0));
        for (int o = t; o < (NPGC * F0) / 4; o += TPB) ((float4*)xs)[o] = xsrc[o];
    }
    __syncthreads();

    // P1: indegree1 + dinv + wave-scan prefix
    if (t < NPGC) {
        int c = 0;
        for (int e = 0; e < EPGC; ++e) c += (s.colm[e] == t);
        s.dinv[t] = rsqrtf(1.0f + (float)c);
        int sc_ = c;
        #pragma unroll
        for (int d = 1; d < 64; d <<= 1) {
            int y = __shfl_up(sc_, d, 64);
            if (t >= d) sc_ += y;
        }
        s.off[t + 1] = (unsigned short)sc_;
        if (t == 0) s.off[0] = 0;
    }
    __syncthreads();

    // P1b: CSR1 fill (stable within-column order)
    if (t < EPGC) {
        const int c = s.colm[t];
        int k = 0;
        for (int e = 0; e < t; ++e) k += (s.colm[e] == c);
        s.erow[s.off[c] + k] = s.rowm[t];
    }
    __syncthreads();

    // P2: xa = N1.x  (preloaded-coefficient gather, 192 threads x 10 feats)
    if (t < 192) {
        const int n = t / 3, q = t - 3 * (t / 3);
        const int i0 = q * 10;
        const int e0 = s.off[n], e1 = s.off[n + 1];
        const int deg = e1 - e0;
        const float dn = s.dinv[n];
        const float cs = dn * dn;
        int er[4]; float ec[4];
        #pragma unroll
        for (int d = 0; d < 4; ++d) {
            const bool vd = d < deg;
            const int j = min(e0 + (vd ? d : 0), EPGC - 1);
            const int r = s.erow[j];
            er[d] = r * F0;
            ec[d] = vd ? s.dinv[r] * dn : 0.f;
        }
        for (int ii = 0; ii < 10; ii += 2) {
            const int i = i0 + ii;
            const float2 xv = *(const float2*)(xs + n * F0 + i);
            float vx = cs * xv.x, vy = cs * xv.y;
            #pragma unroll
            for (int d = 0; d < 4; ++d) {
                const float2 u = *(const float2*)(xs + er[d] + i);
                vx += ec[d] * u.x; vy += ec[d] * u.y;
            }
            for (int j = e0 + 4; j < e1; ++j) {   // rare deg>4 remainder
                const int r = s.erow[j];
                const float c = s.dinv[r] * dn;
                const float2 u = *(const float2*)(xs + r * F0 + i);
                vx += c * u.x; vy += c * u.y;
            }
            float2 o; o.x = vx; o.y = vy;
            *(float2*)(xa + n * F0 + i) = o;
        }
    }
    __syncthreads();

    // P3: h1 = relu(xa @ W1 + b1), 7 rows x 2 cols per thread
    if (t < 250) {
        const int fb = t % 25, nb = t / 25;
        const int f0 = fb * 2;
        float ax[7], ay[7];
        #pragma unroll
        for (int r = 0; r < 7; ++r) { ax[r] = 0.f; ay[r] = 0.f; }
        for (int i = 0; i < F0; i += 2) {
            const float2 wa = *(const float2*)(w1 + i * F1 + f0);
            const float2 wb = *(const float2*)(w1 + (i + 1) * F1 + f0);
            #pragma unroll
            for (int r = 0; r < 7; ++r) {
                const float2 xv = *(const float2*)(xa + (nb + 10 * r) * F0 + i); // in-struct even if n>=64
                ax[r] += xv.x * wa.x + xv.y * wb.x;
                ay[r] += xv.x * wa.y + xv.y * wb.y;
            }
        }
        const float bx = b1[f0], by = b1[f0 + 1];
        #pragma unroll
        for (int r = 0; r < 7; ++r) {
            const int n = nb + 10 * r;
            if (n < NPGC) {
                float2 o; o.x = fmaxf(ax[r] + bx, 0.f); o.y = fmaxf(ay[r] + by, 0.f);
                *(float2*)(h1 + n * F1 + f0) = o;
            }
        }
    }
    __syncthreads();

    // P4: pool1 scores (4 lanes/row + shfl reduce)
    {
        const int n = t >> 2, q = t & 3;
        const int f0 = q * 13, len = (q == 3) ? 11 : 13;
        float a = 0.f, ss = 0.f;
        for (int j = 0; j < len; ++j) {
            const int f = f0 + j;
            const float w = pw1[f];
            ss += w * w;
            a += h1[n * F1 + f] * w;
        }
        a  += __shfl_xor(a, 1);  a  += __shfl_xor(a, 2);
        ss += __shfl_xor(ss, 1); ss += __shfl_xor(ss, 2);
        if (q == 0) s.score[n] = tanhf(a / sqrtf(ss));
    }
    __syncthreads();

    // P5: rank1 (stable descending == jax.lax.top_k)
    if (t < NPGC) {
        const float sc = s.score[t]; int r = 0;
        for (int m = 0; m < NPGC; ++m) {
            const float sm = s.score[m];
            r += (sm > sc) || (sm == sc && m < t);
        }
        s.map[t] = (r < K1C) ? (signed char)r : (signed char)-1;
        if (r < K1C) s.inv[r] = (unsigned char)t;
    }
    __syncthreads();

    // P5b: indegree2 over kept edges + dinv + scan
    if (t < K1C) {
        const int ivt = s.inv[t];
        int c = 0;
        for (int e = 0; e < EPGC; ++e)
            c += (s.colm[e] == ivt) && (s.map[s.rowm[e]] >= 0);
        s.dinv[t] = rsqrtf(1.0f + (float)c);
        int sc_ = c;
        #pragma unroll
        for (int d = 1; d < 64; d <<= 1) {
            int y = __shfl_up(sc_, d, 64);
            if (t >= d) sc_ += y;
        }
        s.off[t + 1] = (unsigned short)sc_;
        if (t == 0) s.off[0] = 0;
    }
    __syncthreads();

    // P5c: CSR2 fill (stores MAPPED src idx)
    if (t < EPGC) {
        const int c = s.colm[t];
        const int mc = s.map[c];
        const int mr = s.map[s.rowm[t]];
        if (mc >= 0 && mr >= 0) {
            int k = 0;
            for (int e = 0; e < t; ++e)
                k += (s.colm[e] == c) && (s.map[s.rowm[e]] >= 0);
            s.erow[s.off[mc] + k] = (unsigned char)mr;
        }
    }
    __syncthreads();

    // P6: ha = N2.(h1[inv]*score)  (preloaded coefs; score folded in)
    if (t < 4 * K1C) {
        const int m = t >> 2, q = t & 3;
        const int i0 = q * 12;
        const int len = (q == 3) ? 14 : 12;
        const int e0 = s.off[m], e1 = s.off[m + 1];
        const int deg = e1 - e0;
        const float dn = s.dinv[m];
        const int ivn = s.inv[m];
        const float cs = dn * dn * s.score[ivn];
        const int rn = ivn * F1;
        int er[4]; float ec[4];
        #pragma unroll
        for (int d = 0; d < 4; ++d) {
            const bool vd = d < deg;
            const int j = min(e0 + (vd ? d : 0), EPGC - 1);
            const int mr = s.erow[j];
            const int ivr = s.inv[mr];
            er[d] = ivr * F1;
            ec[d] = vd ? s.dinv[mr] * dn * s.score[ivr] : 0.f;
        }
        for (int ii = 0; ii < len; ii += 2) {
            const int i = i0 + ii;
            const float2 hv = *(const float2*)(h1 + rn + i);
            float vx = cs * hv.x, vy = cs * hv.y;
            #pragma unroll
            for (int d = 0; d < 4; ++d) {
                const float2 u = *(const float2*)(h1 + er[d] + i);
                vx += ec[d] * u.x; vy += ec[d] * u.y;
            }
            for (int j = e0 + 4; j < e1; ++j) {
                const int mr = s.erow[j];
                const int ivr = s.inv[mr];
                const float c = s.dinv[mr] * dn * s.score[ivr];
                const float2 u = *(const float2*)(h1 + ivr * F1 + i);
                vx += c * u.x; vy += c * u.y;
            }
            float2 o; o.x = vx; o.y = vy;
            *(float2*)(ha + m * F1 + i) = o;
        }
    }
    __syncthreads();

    // P7: h2 = relu(ha @ W2 + b2), 6 rows x 4 cols per thread (overwrites h1 region)
    if (t < 250) {
        const int fb = t % 25, nb = t / 25;
        const int f0 = fb * 4;
        float4 acc[6];
        #pragma unroll
        for (int r = 0; r < 6; ++r) { acc[r].x = 0.f; acc[r].y = 0.f; acc[r].z = 0.f; acc[r].w = 0.f; }
        for (int i = 0; i < F1; i += 2) {
            const float4 wa = *(const float4*)(w2 + i * F2 + f0);
            const float4 wb = *(const float4*)(w2 + (i + 1) * F2 + f0);
            #pragma unroll
            for (int r = 0; r < 6; ++r) {
                const float2 hv = *(const float2*)(ha + (nb + 10 * r) * F1 + i); // in-struct even if m>=52
                acc[r].x += hv.x * wa.x + hv.y * wb.x;
                acc[r].y += hv.x * wa.y + hv.y * wb.y;
                acc[r].z += hv.x * wa.z + hv.y * wb.z;
                acc[r].w += hv.x * wa.w + hv.y * wb.w;
            }
        }
        const float4 bb = *(const float4*)(cb2 + f0);
        #pragma unroll
        for (int r = 0; r < 6; ++r) {
            const int m = nb + 10 * r;
            if (m < K1C) {
                float4 o;
                o.x = fmaxf(acc[r].x + bb.x, 0.f);
                o.y = fmaxf(acc[r].y + bb.y, 0.f);
                o.z = fmaxf(acc[r].z + bb.z, 0.f);
                o.w = fmaxf(acc[r].w + bb.w, 0.f);
                *(float4*)(h2 + m * F2 + f0) = o;
            }
        }
    }
    __syncthreads();

    // P8: pool2 scores (pure h2 reads)
    if (t < 4 * K1C) {
        const int m = t >> 2, q = t & 3;
        const int f0 = q * 25;
        float a = 0.f, ss = 0.f;
        for (int j = 0; j < 25; ++j) {
            const int f = f0 + j;
            const float w = pw2[f];
            ss += w * w;
            a += h2[m * F2 + f] * w;
        }
        a  += __shfl_xor(a, 1);  a  += __shfl_xor(a, 2);
        ss += __shfl_xor(ss, 1); ss += __shfl_xor(ss, 2);
        if (q == 0) s.score2[m] = tanhf(a / sqrtf(ss));
    }
    __syncthreads();

    // P9: rank2
    if (t < K1C) {
        const float sc = s.score2[t]; int r = 0;
        for (int m = 0; m < K1C; ++m) {
            const float sm = s.score2[m];
            r += (sm > sc) || (sm == sc && m < t);
        }
        if (r < K2C) s.inv2[r] = (unsigned char)t;
    }
    __syncthreads();

    // P10: readout partials (two row-halves x 100 feats)
    if (t < 200) {
        const int f = t % 100, hh = t / 100;
        float mx = -INFINITY, sm = 0.f;
        for (int r = hh * 21; r < hh * 21 + 21; ++r) {
            const int n = s.inv2[r];
            const float y = h2[n * F2 + f] * s.score2[n];
            mx = fmaxf(mx, y);
            sm += y;
        }
        rd[hh * 100 + f]       = mx;
        rd[200 + hh * 100 + f] = sm;
    }
    __syncthreads();

    // P11: combine + write pooled
    if (t < F2) {
        float* pd = ws_pooled + (size_t)g * 200;
        pd[t]       = fmaxf(rd[t], rd[100 + t]);
        pd[100 + t] = (rd[200 + t] + rd[300 + t]) * (1.0f / (float)K2C);
    }
}

// ---------------- head kernel: 4 graphs/block, 2048 blocks = 8 blocks/CU ----------------
#define GPB 4
struct HS {
    union {
        float sp[GPB * 201];
        struct { float d1[GPB * 100]; float d2[GPB * 201]; } b;
    } u;
    float le[GPB * 201];
    float muv[GPB * 50];
    int   sls[GPB];
};

__global__ __launch_bounds__(TPB, 8)
void molgen_head(const float* __restrict__ ws_pooled,
                 const int* __restrict__ smile_len,
                 const float* __restrict__ emb,
                 const float* __restrict__ mean_w,   const float* __restrict__ mean_b,
                 const float* __restrict__ logvar_w, const float* __restrict__ logvar_b,
                 const float* __restrict__ dec1_w, const float* __restrict__ dec1_b,
                 const float* __restrict__ dec2_w, const float* __restrict__ dec2_b,
                 const float* __restrict__ out_w,  const float* __restrict__ out_b,
                 float* __restrict__ out, int B)
{
    __shared__ HS h;
    const int t  = threadIdx.x;
    const int g0 = blockIdx.x * GPB;

    if (t < GPB) h.sls[t] = (g0 + t < B) ? smile_len[g0 + t] : 0;
    __syncthreads();
    for (int o = t; o < GPB * 200; o += TPB) {
        const int gg = o / 200, f = o - gg * 200;
        h.u.sp[gg * 201 + f] = ws_pooled[(size_t)(g0 + gg) * 200 + f];
        h.le[gg * 201 + f]   = fmaxf(emb[(size_t)h.sls[gg] * 200 + f], 0.f);
    }
    __syncthreads();

    // mu & logvar: 1 graph per thread
    if (t < 200) {
        const int j = t % 50, gg = t / 50;
        float am = mean_b[j], al = logvar_b[j];
        const float* sp = &h.u.sp[gg * 201];
        for (int i = 0; i < 200; ++i) {
            const float p = sp[i];
            am += p * mean_w[i * 50 + j];
            al += p * logvar_w[i * 50 + j];
        }
        am = fmaxf(am, 0.f);
        h.muv[gg * 50 + j] = am;
        out[(size_t)B * 200 + (size_t)(g0 + gg) * 50 + j] = am;
        out[(size_t)B * 250 + (size_t)(g0 + gg) * 50 + j] = fmaxf(al, 0.f);
    }
    __syncthreads();   // sp dead; d1 aliases it

    // d1 = relu([mu, lemb] @ dec1_w + b): 2 graphs per thread
    if (t < 200) {
        const int j = t % 100, gh = t / 100;
        const float* mv0 = &h.muv[(gh * 2) * 50];
        const float* mv1 = &h.muv[(gh * 2 + 1) * 50];
        const float* le0 = &h.le[(gh * 2) * 201];
        const float* le1 = &h.le[(gh * 2 + 1) * 201];
        float a0 = dec1_b[j], a1 = a0;
        for (int i = 0; i < 50; ++i) {
            const float w = dec1_w[i * 100 + j];
            a0 += mv0[i] * w; a1 += mv1[i] * w;
        }
        for (int i = 0; i < 200; ++i) {
            const float w = dec1_w[(50 + i) * 100 + j];
            a0 += le0[i] * w; a1 += le1[i] * w;
        }
        h.u.b.d1[(gh * 2) * 100 + j]     = fmaxf(a0, 0.f);
        h.u.b.d1[(gh * 2 + 1) * 100 + j] = fmaxf(a1, 0.f);
    }
    __syncthreads();

    // d2 = relu(d1 @ dec2_w + b) + lemb: 4 graphs per thread
    if (t < 200) {
        const int j = t;
        float a[GPB];
        #pragma unroll
        for (int k = 0; k < GPB; ++k) a[k] = dec2_b[j];
        for (int i = 0; i < 100; ++i) {
            const float w = dec2_w[i * 200 + j];
            #pragma unroll
            for (int k = 0; k < GPB; ++k) a[k] += h.u.b.d1[k * 100 + i] * w;
        }
        #pragma unroll
        for (int k = 0; k < GPB; ++k)
            h.u.b.d2[k * 201 + j] = fmaxf(a[k], 0.f) + h.le[k * 201 + j];
    }
    __syncthreads();

    // out = relu(d2 @ out_w + b)
    if (t < 200) {
        const int j = t;
        float a[GPB];
        #pragma unroll
        for (int k = 0; k < GPB; ++k) a[k] = out_b[j];
        for (int i = 0; i < 200; ++i) {
            const float w = out_w[i * 200 + j];
            #pragma unroll
            for (int k = 0; k < GPB; ++k) a[k] += h.u.b.d2[k * 201 + i] * w;
        }
        #pragma unroll
        for (int k = 0; k < GPB; ++k)
            if (g0 + k < B) out[(size_t)(g0 + k) * 200 + j] = fmaxf(a[k], 0.f);
    }
}

extern "C" void kernel_launch(void* const* d_in, const int* in_sizes, int n_in,
                              void* d_out, int out_size, void* d_ws, size_t ws_size,
                              hipStream_t stream) {
    const float* x        = (const float*)d_in[0];
    const int*   ei       = (const int*)d_in[1];
    const int*   slen     = (const int*)d_in[3];
    const float* w1       = (const float*)d_in[4];
    const float* b1       = (const float*)d_in[5];
    const float* pw1      = (const float*)d_in[6];
    const float* w2       = (const float*)d_in[7];
    const float* b2       = (const float*)d_in[8];
    const float* pw2      = (const float*)d_in[9];
    const float* mean_w   = (const float*)d_in[10];
    const float* mean_b   = (const float*)d_in[11];
    const float* logvar_w = (const float*)d_in[12];
    const float* logvar_b = (const float*)d_in[13];
    const float* emb      = (const float*)d_in[14];
    const float* dec1_w   = (const float*)d_in[15];
    const float* dec1_b   = (const float*)d_in[16];
    const float* dec2_w   = (const float*)d_in[17];
    const float* dec2_b   = (const float*)d_in[18];
    const float* out_w    = (const float*)d_in[19];
    const float* out_b    = (const float*)d_in[20];

    const int B = in_sizes[3];
    const int E = in_sizes[1] / 2;

    float* pooled = (float*)d_ws;   // [B][200] fp32

    molgen_graph<<<B, TPB, 0, stream>>>(x, ei, w1, b1, pw1, w2, b2, pw2, pooled, E);
    molgen_head<<<(B + GPB - 1) / GPB, TPB, 0, stream>>>(pooled, slen, emb,
        mean_w, mean_b, logvar_w, logvar_b, dec1_w, dec1_b, dec2_w, dec2_b,
        out_w, out_b, (float*)d_out, B);
}

// Round 8
// 663.551 us; speedup vs baseline: 1.1319x; 1.1319x over previous
//
#include <hip/hip_runtime.h>
#include <math.h>

#define TPB  256
#define NPGC 64
#define EPGC 128
#define K1C  52
#define K2C  42
#define F0   30
#define F1   50
#define F2   100

// ---------------- graph kernel ----------------
// LDS 32KB -> 5 blocks/CU (LDS-limited; launch_bounds kept at 4 to avoid spill heuristics).
// Region A (20800B floats): h1[64][50] | xa[64][30] @ +3200  ->  h2[52][100]
// Region B (2600 floats):   xs[64][30] -> ha[52][50] -> rd[400]
// GCN aggregation-first: h = relu(N.(x) @ W + b) with N = D^-1/2 (A+I) D^-1/2
#define H1(n,f)  s.A[(n) * F1 + (f)]
#define XA(n,i)  s.A[3200 + (n) * F0 + (i)]
#define H2(m,f)  s.A[(m) * F2 + (f)]
#define XS(n,i)  s.B[(n) * F0 + (i)]
#define HA(m,i)  s.B[(m) * F1 + (i)]
#define RD(k)    s.B[(k)]

struct GS {
    float A[5200] __attribute__((aligned(16)));
    float B[2600] __attribute__((aligned(16)));
    float dinv[NPGC];
    float score[NPGC];
    float score2[K1C];
    unsigned short off[NPGC + 1];
    unsigned char rowm[EPGC];
    unsigned char colm[EPGC];
    unsigned char erow[EPGC];   // CSR1: src node; CSR2: mapped src (pooled idx)
    unsigned char inv[NPGC];
    unsigned char inv2[K2C + 2];
    signed char   map[NPGC];
};

__global__ __launch_bounds__(TPB, 4)
void molgen_graph(const float* __restrict__ x,
                  const int* __restrict__ ei,
                  const float* __restrict__ w1,  const float* __restrict__ b1,
                  const float* __restrict__ pw1,
                  const float* __restrict__ w2,  const float* __restrict__ cb2,
                  const float* __restrict__ pw2,
                  float* __restrict__ ws_pooled,
                  int E)
{
    __shared__ GS s;
    const int g = blockIdx.x;
    const int t = threadIdx.x;

    // P0: edges (u8 local ids) + stage x (float4)
    if (t < EPGC) {
        s.rowm[t] = (unsigned char)(ei[(size_t)g * EPGC + t] - g * NPGC);
        s.colm[t] = (unsigned char)(ei[(size_t)E + (size_t)g * EPGC + t] - g * NPGC);
    }
    {
        const float4* xsrc = (const float4*)(x + (size_t)g * (NPGC * F0));
        for (int o = t; o < (NPGC * F0) / 4; o += TPB) ((float4*)s.B)[o] = xsrc[o];
    }
    __syncthreads();

    // P1: indegree1 + dinv + wave-scan prefix
    if (t < NPGC) {
        int c = 0;
        for (int e = 0; e < EPGC; ++e) c += (s.colm[e] == t);
        s.dinv[t] = rsqrtf(1.0f + (float)c);
        int sc_ = c;
        #pragma unroll
        for (int d = 1; d < 64; d <<= 1) {
            int y = __shfl_up(sc_, d, 64);
            if (t >= d) sc_ += y;
        }
        s.off[t + 1] = (unsigned short)sc_;
        if (t == 0) s.off[0] = 0;
    }
    __syncthreads();

    // P1b: CSR1 fill (stable within-column order)
    if (t < EPGC) {
        const int c = s.colm[t];
        int k = 0;
        for (int e = 0; e < t; ++e) k += (s.colm[e] == c);
        s.erow[s.off[c] + k] = s.rowm[t];
    }
    __syncthreads();

    // P2: xa = N1.x  (preloaded-coefficient gather, 192 threads x 10 feats)
    if (t < 192) {
        const int n = t / 3, q = t - 3 * (t / 3);
        const int i0 = q * 10;
        const int e0 = s.off[n], e1 = s.off[n + 1];
        const int deg = e1 - e0;
        const float dn = s.dinv[n];
        const float cs = dn * dn;
        int er0, er1, er2, er3; float ec0, ec1, ec2, ec3;
        {
            const int j0 = min(e0 + 0, EPGC - 1), r0 = s.erow[j0];
            const int j1 = min(e0 + 1, EPGC - 1), r1 = s.erow[j1];
            const int j2 = min(e0 + 2, EPGC - 1), r2 = s.erow[j2];
            const int j3 = min(e0 + 3, EPGC - 1), r3 = s.erow[j3];
            er0 = r0 * F0; ec0 = (0 < deg) ? s.dinv[r0] * dn : 0.f;
            er1 = r1 * F0; ec1 = (1 < deg) ? s.dinv[r1] * dn : 0.f;
            er2 = r2 * F0; ec2 = (2 < deg) ? s.dinv[r2] * dn : 0.f;
            er3 = r3 * F0; ec3 = (3 < deg) ? s.dinv[r3] * dn : 0.f;
        }
        for (int ii = 0; ii < 10; ii += 2) {
            const int i = i0 + ii;
            const float2 xv = *(const float2*)(&XS(n, i));
            float vx = cs * xv.x, vy = cs * xv.y;
            {
                const float2 u0 = *(const float2*)(&s.B[er0 + i]);
                const float2 u1 = *(const float2*)(&s.B[er1 + i]);
                const float2 u2 = *(const float2*)(&s.B[er2 + i]);
                const float2 u3 = *(const float2*)(&s.B[er3 + i]);
                vx += ec0 * u0.x + ec1 * u1.x + ec2 * u2.x + ec3 * u3.x;
                vy += ec0 * u0.y + ec1 * u1.y + ec2 * u2.y + ec3 * u3.y;
            }
            for (int j = e0 + 4; j < e1; ++j) {   // rare deg>4 remainder
                const int r = s.erow[j];
                const float c = s.dinv[r] * dn;
                const float2 u = *(const float2*)(&XS(r, i));
                vx += c * u.x; vy += c * u.y;
            }
            float2 o; o.x = vx; o.y = vy;
            *(float2*)(&XA(n, i)) = o;
        }
    }
    __syncthreads();

    // P3: h1 = relu(xa @ W1 + b1), 7 rows x 2 cols per thread
    if (t < 250) {
        const int fb = t % 25, nb = t / 25;
        const int f0 = fb * 2;
        float ax[7], ay[7];
        #pragma unroll
        for (int r = 0; r < 7; ++r) { ax[r] = 0.f; ay[r] = 0.f; }
        for (int i = 0; i < F0; i += 2) {
            const float2 wa = *(const float2*)(w1 + i * F1 + f0);
            const float2 wb = *(const float2*)(w1 + (i + 1) * F1 + f0);
            #pragma unroll
            for (int r = 0; r < 7; ++r) {
                const float2 xv = *(const float2*)(&XA(nb + 10 * r, i)); // in-struct even if n>=64
                ax[r] += xv.x * wa.x + xv.y * wb.x;
                ay[r] += xv.x * wa.y + xv.y * wb.y;
            }
        }
        const float bx = b1[f0], by = b1[f0 + 1];
        #pragma unroll
        for (int r = 0; r < 7; ++r) {
            const int n = nb + 10 * r;
            if (n < NPGC) {
                float2 o; o.x = fmaxf(ax[r] + bx, 0.f); o.y = fmaxf(ay[r] + by, 0.f);
                *(float2*)(&H1(n, f0)) = o;
            }
        }
    }
    __syncthreads();

    // P4: pool1 scores (4 lanes/row + shfl reduce)
    {
        const int n = t >> 2, q = t & 3;
        const int f0 = q * 13, len = (q == 3) ? 11 : 13;
        float a = 0.f, ss = 0.f;
        for (int j = 0; j < len; ++j) {
            const int f = f0 + j;
            const float w = pw1[f];
            ss += w * w;
            a += H1(n, f) * w;
        }
        a  += __shfl_xor(a, 1);  a  += __shfl_xor(a, 2);
        ss += __shfl_xor(ss, 1); ss += __shfl_xor(ss, 2);
        if (q == 0) s.score[n] = tanhf(a / sqrtf(ss));
    }
    __syncthreads();

    // P5: rank1 (stable descending == jax.lax.top_k)
    if (t < NPGC) {
        const float sc = s.score[t]; int r = 0;
        for (int m = 0; m < NPGC; ++m) {
            const float sm = s.score[m];
            r += (sm > sc) || (sm == sc && m < t);
        }
        s.map[t] = (r < K1C) ? (signed char)r : (signed char)-1;
        if (r < K1C) s.inv[r] = (unsigned char)t;
    }
    __syncthreads();

    // P5b: indegree2 over kept edges + dinv + scan
    if (t < K1C) {
        const int ivt = s.inv[t];
        int c = 0;
        for (int e = 0; e < EPGC; ++e)
            c += (s.colm[e] == ivt) && (s.map[s.rowm[e]] >= 0);
        s.dinv[t] = rsqrtf(1.0f + (float)c);
        int sc_ = c;
        #pragma unroll
        for (int d = 1; d < 64; d <<= 1) {
            int y = __shfl_up(sc_, d, 64);
            if (t >= d) sc_ += y;
        }
        s.off[t + 1] = (unsigned short)sc_;
        if (t == 0) s.off[0] = 0;
    }
    __syncthreads();

    // P5c: CSR2 fill (stores MAPPED src idx)
    if (t < EPGC) {
        const int c = s.colm[t];
        const int mc = s.map[c];
        const int mr = s.map[s.rowm[t]];
        if (mc >= 0 && mr >= 0) {
            int k = 0;
            for (int e = 0; e < t; ++e)
                k += (s.colm[e] == c) && (s.map[s.rowm[e]] >= 0);
            s.erow[s.off[mc] + k] = (unsigned char)mr;
        }
    }
    __syncthreads();

    // P6: ha = N2.(h1[inv]*score)  (preloaded coefs; score folded in)
    if (t < 4 * K1C) {
        const int m = t >> 2, q = t & 3;
        const int i0 = q * 12;
        const int len = (q == 3) ? 14 : 12;
        const int e0 = s.off[m], e1 = s.off[m + 1];
        const int deg = e1 - e0;
        const float dn = s.dinv[m];
        const int ivn = s.inv[m];
        const float cs = dn * dn * s.score[ivn];
        const int rn = ivn * F1;
        int er0, er1, er2, er3; float ec0, ec1, ec2, ec3;
        {
            const int j0 = min(e0 + 0, EPGC - 1); const int m0 = s.erow[j0]; const int v0 = s.inv[m0];
            const int j1 = min(e0 + 1, EPGC - 1); const int m1 = s.erow[j1]; const int v1 = s.inv[m1];
            const int j2 = min(e0 + 2, EPGC - 1); const int m2 = s.erow[j2]; const int v2 = s.inv[m2];
            const int j3 = min(e0 + 3, EPGC - 1); const int m3 = s.erow[j3]; const int v3 = s.inv[m3];
            er0 = v0 * F1; ec0 = (0 < deg) ? s.dinv[m0] * dn * s.score[v0] : 0.f;
            er1 = v1 * F1; ec1 = (1 < deg) ? s.dinv[m1] * dn * s.score[v1] : 0.f;
            er2 = v2 * F1; ec2 = (2 < deg) ? s.dinv[m2] * dn * s.score[v2] : 0.f;
            er3 = v3 * F1; ec3 = (3 < deg) ? s.dinv[m3] * dn * s.score[v3] : 0.f;
        }
        for (int ii = 0; ii < len; ii += 2) {
            const int i = i0 + ii;
            const float2 hv = *(const float2*)(&s.A[rn + i]);
            float vx = cs * hv.x, vy = cs * hv.y;
            {
                const float2 u0 = *(const float2*)(&s.A[er0 + i]);
                const float2 u1 = *(const float2*)(&s.A[er1 + i]);
                const float2 u2 = *(const float2*)(&s.A[er2 + i]);
                const float2 u3 = *(const float2*)(&s.A[er3 + i]);
                vx += ec0 * u0.x + ec1 * u1.x + ec2 * u2.x + ec3 * u3.x;
                vy += ec0 * u0.y + ec1 * u1.y + ec2 * u2.y + ec3 * u3.y;
            }
            for (int j = e0 + 4; j < e1; ++j) {
                const int mr = s.erow[j];
                const int ivr = s.inv[mr];
                const float c = s.dinv[mr] * dn * s.score[ivr];
                const float2 u = *(const float2*)(&s.A[ivr * F1 + i]);
                vx += c * u.x; vy += c * u.y;
            }
            float2 o; o.x = vx; o.y = vy;
            *(float2*)(&HA(m, i)) = o;
        }
    }
    __syncthreads();

    // P7: h2 = relu(ha @ W2 + b2), 6 rows x 4 cols per thread (overwrites h1 region)
    if (t < 250) {
        const int fb = t % 25, nb = t / 25;
        const int f0 = fb * 4;
        float4 acc[6];
        #pragma unroll
        for (int r = 0; r < 6; ++r) { acc[r].x = 0.f; acc[r].y = 0.f; acc[r].z = 0.f; acc[r].w = 0.f; }
        for (int i = 0; i < F1; i += 2) {
            const float4 wa = *(const float4*)(w2 + i * F2 + f0);
            const float4 wb = *(const float4*)(w2 + (i + 1) * F2 + f0);
            #pragma unroll
            for (int r = 0; r < 6; ++r) {
                const float2 hv = *(const float2*)(&HA(nb + 10 * r, i)); // in-struct even if m>=52
                acc[r].x += hv.x * wa.x + hv.y * wb.x;
                acc[r].y += hv.x * wa.y + hv.y * wb.y;
                acc[r].z += hv.x * wa.z + hv.y * wb.z;
                acc[r].w += hv.x * wa.w + hv.y * wb.w;
            }
        }
        const float4 bb = *(const float4*)(cb2 + f0);
        #pragma unroll
        for (int r = 0; r < 6; ++r) {
            const int m = nb + 10 * r;
            if (m < K1C) {
                float4 o;
                o.x = fmaxf(acc[r].x + bb.x, 0.f);
                o.y = fmaxf(acc[r].y + bb.y, 0.f);
                o.z = fmaxf(acc[r].z + bb.z, 0.f);
                o.w = fmaxf(acc[r].w + bb.w, 0.f);
                *(float4*)(&H2(m, f0)) = o;
            }
        }
    }
    __syncthreads();

    // P8: pool2 scores (pure h2 reads)
    if (t < 4 * K1C) {
        const int m = t >> 2, q = t & 3;
        const int f0 = q * 25;
        float a = 0.f, ss = 0.f;
        for (int j = 0; j < 25; ++j) {
            const int f = f0 + j;
            const float w = pw2[f];
            ss += w * w;
            a += H2(m, f) * w;
        }
        a  += __shfl_xor(a, 1);  a  += __shfl_xor(a, 2);
        ss += __shfl_xor(ss, 1); ss += __shfl_xor(ss, 2);
        if (q == 0) s.score2[m] = tanhf(a / sqrtf(ss));
    }
    __syncthreads();

    // P9: rank2
    if (t < K1C) {
        const float sc = s.score2[t]; int r = 0;
        for (int m = 0; m < K1C; ++m) {
            const float sm = s.score2[m];
            r += (sm > sc) || (sm == sc && m < t);
        }
        if (r < K2C) s.inv2[r] = (unsigned char)t;
    }
    __syncthreads();

    // P10: readout partials (two row-halves x 100 feats)
    if (t < 200) {
        const int f = t % 100, hh = t / 100;
        float mx = -INFINITY, sm = 0.f;
        for (int r = hh * 21; r < hh * 21 + 21; ++r) {
            const int n = s.inv2[r];
            const float y = H2(n, f) * s.score2[n];
            mx = fmaxf(mx, y);
            sm += y;
        }
        // rd overwrites ha region AFTER all h2 reads (h2 is in A; rd in B) — safe:
        RD(hh * 100 + f)       = mx;
        RD(200 + hh * 100 + f) = sm;
    }
    __syncthreads();

    // P11: combine + write pooled
    if (t < F2) {
        float* pd = ws_pooled + (size_t)g * 200;
        pd[t]       = fmaxf(RD(t), RD(100 + t));
        pd[100 + t] = (RD(200 + t) + RD(300 + t)) * (1.0f / (float)K2C);
    }
}

// ---------------- head kernel: 4 graphs/block, 2048 blocks = 8 blocks/CU ----------------
#define GPB 4
struct HS {
    union {
        float sp[GPB * 201];
        struct { float d1[GPB * 100]; float d2[GPB * 201]; } b;
    } u;
    float le[GPB * 201];
    float muv[GPB * 50];
    int   sls[GPB];
};

__global__ __launch_bounds__(TPB, 8)
void molgen_head(const float* __restrict__ ws_pooled,
                 const int* __restrict__ smile_len,
                 const float* __restrict__ emb,
                 const float* __restrict__ mean_w,   const float* __restrict__ mean_b,
                 const float* __restrict__ logvar_w, const float* __restrict__ logvar_b,
                 const float* __restrict__ dec1_w, const float* __restrict__ dec1_b,
                 const float* __restrict__ dec2_w, const float* __restrict__ dec2_b,
                 const float* __restrict__ out_w,  const float* __restrict__ out_b,
                 float* __restrict__ out, int B)
{
    __shared__ HS h;
    const int t  = threadIdx.x;
    const int g0 = blockIdx.x * GPB;

    if (t < GPB) h.sls[t] = (g0 + t < B) ? smile_len[g0 + t] : 0;
    __syncthreads();
    for (int o = t; o < GPB * 200; o += TPB) {
        const int gg = o / 200, f = o - gg * 200;
        h.u.sp[gg * 201 + f] = ws_pooled[(size_t)(g0 + gg) * 200 + f];
        h.le[gg * 201 + f]   = fmaxf(emb[(size_t)h.sls[gg] * 200 + f], 0.f);
    }
    __syncthreads();

    // mu & logvar: 1 graph per thread
    if (t < 200) {
        const int j = t % 50, gg = t / 50;
        float am = mean_b[j], al = logvar_b[j];
        const float* sp = &h.u.sp[gg * 201];
        for (int i = 0; i < 200; ++i) {
            const float p = sp[i];
            am += p * mean_w[i * 50 + j];
            al += p * logvar_w[i * 50 + j];
        }
        am = fmaxf(am, 0.f);
        h.muv[gg * 50 + j] = am;
        out[(size_t)B * 200 + (size_t)(g0 + gg) * 50 + j] = am;
        out[(size_t)B * 250 + (size_t)(g0 + gg) * 50 + j] = fmaxf(al, 0.f);
    }
    __syncthreads();   // sp dead; d1 aliases it

    // d1 = relu([mu, lemb] @ dec1_w + b): 2 graphs per thread
    if (t < 200) {
        const int j = t % 100, gh = t / 100;
        const float* mv0 = &h.muv[(gh * 2) * 50];
        const float* mv1 = &h.muv[(gh * 2 + 1) * 50];
        const float* le0 = &h.le[(gh * 2) * 201];
        const float* le1 = &h.le[(gh * 2 + 1) * 201];
        float a0 = dec1_b[j], a1 = a0;
        for (int i = 0; i < 50; ++i) {
            const float w = dec1_w[i * 100 + j];
            a0 += mv0[i] * w; a1 += mv1[i] * w;
        }
        for (int i = 0; i < 200; ++i) {
            const float w = dec1_w[(50 + i) * 100 + j];
            a0 += le0[i] * w; a1 += le1[i] * w;
        }
        h.u.b.d1[(gh * 2) * 100 + j]     = fmaxf(a0, 0.f);
        h.u.b.d1[(gh * 2 + 1) * 100 + j] = fmaxf(a1, 0.f);
    }
    __syncthreads();

    // d2 = relu(d1 @ dec2_w + b) + lemb: 4 graphs per thread
    if (t < 200) {
        const int j = t;
        float a[GPB];
        #pragma unroll
        for (int k = 0; k < GPB; ++k) a[k] = dec2_b[j];
        for (int i = 0; i < 100; ++i) {
            const float w = dec2_w[i * 200 + j];
            #pragma unroll
            for (int k = 0; k < GPB; ++k) a[k] += h.u.b.d1[k * 100 + i] * w;
        }
        #pragma unroll
        for (int k = 0; k < GPB; ++k)
            h.u.b.d2[k * 201 + j] = fmaxf(a[k], 0.f) + h.le[k * 201 + j];
    }
    __syncthreads();

    // out = relu(d2 @ out_w + b)
    if (t < 200) {
        const int j = t;
        float a[GPB];
        #pragma unroll
        for (int k = 0; k < GPB; ++k) a[k] = out_b[j];
        for (int i = 0; i < 200; ++i) {
            const float w = out_w[i * 200 + j];
            #pragma unroll
            for (int k = 0; k < GPB; ++k) a[k] += h.u.b.d2[k * 201 + i] * w;
        }
        #pragma unroll
        for (int k = 0; k < GPB; ++k)
            if (g0 + k < B) out[(size_t)(g0 + k) * 200 + j] = fmaxf(a[k], 0.f);
    }
}

extern "C" void kernel_launch(void* const* d_in, const int* in_sizes, int n_in,
                              void* d_out, int out_size, void* d_ws, size_t ws_size,
                              hipStream_t stream) {
    const float* x        = (const float*)d_in[0];
    const int*   ei       = (const int*)d_in[1];
    const int*   slen     = (const int*)d_in[3];
    const float* w1       = (const float*)d_in[4];
    const float* b1       = (const float*)d_in[5];
    const float* pw1      = (const float*)d_in[6];
    const float* w2       = (const float*)d_in[7];
    const float* b2       = (const float*)d_in[8];
    const float* pw2      = (const float*)d_in[9];
    const float* mean_w   = (const float*)d_in[10];
    const float* mean_b   = (const float*)d_in[11];
    const float* logvar_w = (const float*)d_in[12];
    const float* logvar_b = (const float*)d_in[13];
    const float* emb      = (const float*)d_in[14];
    const float* dec1_w   = (const float*)d_in[15];
    const float* dec1_b   = (const float*)d_in[16];
    const float* dec2_w   = (const float*)d_in[17];
    const float* dec2_b   = (const float*)d_in[18];
    const float* out_w    = (const float*)d_in[19];
    const float* out_b    = (const float*)d_in[20];

    const int B = in_sizes[3];
    const int E = in_sizes[1] / 2;

    float* pooled = (float*)d_ws;   // [B][200] fp32

    molgen_graph<<<B, TPB, 0, stream>>>(x, ei, w1, b1, pw1, w2, b2, pw2, pooled, E);
    molgen_head<<<(B + GPB - 1) / GPB, TPB, 0, stream>>>(pooled, slen, emb,
        mean_w, mean_b, logvar_w, logvar_b, dec1_w, dec1_b, dec2_w, dec2_b,
        out_w, out_b, (float*)d_out, B);
}

// Round 9
// 405.563 us; speedup vs baseline: 1.8519x; 1.6361x over previous
//
#include <hip/hip_runtime.h>
#include <math.h>

#define TPB  256
#define NPGC 64
#define EPGC 128
#define K1C  52
#define K2C  42
#define F0   30
#define F1   50
#define F2   100

// ---------------- graph kernel ----------------
// Region A (5200 floats): h1[64][50] | xa[64][30] @ +3200  ->  h2[52][100]
// Region B (2600 floats): xs[64][30] -> ha[52][50] -> rd[400]
// GCN aggregation-first: h = relu((N.x) @ W + b), N = D^-1/2 (A+I) D^-1/2
// CSR built with LDS atomics (indegree + slot alloc) — no quadratic loops.
#define H1(n,f)  s.A[(n) * F1 + (f)]
#define XA(n,i)  s.A[3200 + (n) * F0 + (i)]
#define H2(m,f)  s.A[(m) * F2 + (f)]
#define XS(n,i)  s.B[(n) * F0 + (i)]
#define HA(m,i)  s.B[(m) * F1 + (i)]
#define RD(k)    s.B[(k)]

struct GS {
    float A[5200] __attribute__((aligned(16)));
    float B[2600] __attribute__((aligned(16)));
    int   cnt[NPGC];
    int   ecnt[NPGC];
    float dinv[NPGC];
    float score[NPGC];
    float score2[K1C];
    unsigned short off[NPGC + 1];
    unsigned char rowm[EPGC];
    unsigned char colm[EPGC];   // 255 == dropped (conv2)
    unsigned char erow[EPGC];   // CSR1: src node; CSR2: mapped src (pooled idx)
    unsigned char inv[NPGC];
    unsigned char inv2[K2C + 2];
    signed char   map[NPGC];
};

__global__ __launch_bounds__(TPB, 4)
void molgen_graph(const float* __restrict__ x,
                  const int* __restrict__ ei,
                  const float* __restrict__ w1,  const float* __restrict__ b1,
                  const float* __restrict__ pw1,
                  const float* __restrict__ w2,  const float* __restrict__ cb2,
                  const float* __restrict__ pw2,
                  float* __restrict__ ws_pooled,
                  int E)
{
    __shared__ GS s;
    const int g = blockIdx.x;
    const int t = threadIdx.x;

    // P0: zero counters + edges (u8 local ids) + stage x (float4)
    if (t < NPGC) s.cnt[t] = 0;
    if (t < EPGC) {
        s.rowm[t] = (unsigned char)(ei[(size_t)g * EPGC + t] - g * NPGC);
        s.colm[t] = (unsigned char)(ei[(size_t)E + (size_t)g * EPGC + t] - g * NPGC);
    }
    {
        const float4* xsrc = (const float4*)(x + (size_t)g * (NPGC * F0));
        for (int o = t; o < (NPGC * F0) / 4; o += TPB) ((float4*)s.B)[o] = xsrc[o];
    }
    __syncthreads();

    // P1: indegree1 via atomics
    if (t < EPGC) atomicAdd(&s.cnt[s.colm[t]], 1);
    __syncthreads();

    // P2: dinv + wave-scan prefix -> off ; zero slot counters
    if (t < NPGC) {
        const int c = s.cnt[t];
        s.dinv[t] = rsqrtf(1.0f + (float)c);
        int sc_ = c;
        #pragma unroll
        for (int d = 1; d < 64; d <<= 1) {
            int y = __shfl_up(sc_, d, 64);
            if (t >= d) sc_ += y;
        }
        s.off[t + 1] = (unsigned short)sc_;
        if (t == 0) s.off[0] = 0;
        s.ecnt[t] = 0;
    }
    __syncthreads();

    // P3: CSR1 fill via atomic slot alloc (within-col order nondeterministic — sum reorder only)
    if (t < EPGC) {
        const int c = s.colm[t];
        const int k = atomicAdd(&s.ecnt[c], 1);
        s.erow[s.off[c] + k] = s.rowm[t];
    }
    __syncthreads();

    // P4: xa = N1.x  (preloaded-coefficient gather, 192 threads x 10 feats)
    if (t < 192) {
        const int n = t / 3, q = t - 3 * (t / 3);
        const int i0 = q * 10;
        const int e0 = s.off[n], e1 = s.off[n + 1];
        const int deg = e1 - e0;
        const float dn = s.dinv[n];
        const float cs = dn * dn;
        int er0, er1, er2, er3; float ec0, ec1, ec2, ec3;
        {
            const int r0 = (0 < deg) ? s.erow[e0 + 0] : 0;
            const int r1 = (1 < deg) ? s.erow[e0 + 1] : 0;
            const int r2 = (2 < deg) ? s.erow[e0 + 2] : 0;
            const int r3 = (3 < deg) ? s.erow[e0 + 3] : 0;
            er0 = r0 * F0; ec0 = (0 < deg) ? s.dinv[r0] * dn : 0.f;
            er1 = r1 * F0; ec1 = (1 < deg) ? s.dinv[r1] * dn : 0.f;
            er2 = r2 * F0; ec2 = (2 < deg) ? s.dinv[r2] * dn : 0.f;
            er3 = r3 * F0; ec3 = (3 < deg) ? s.dinv[r3] * dn : 0.f;
        }
        for (int ii = 0; ii < 10; ii += 2) {
            const int i = i0 + ii;
            const float2 xv = *(const float2*)(&XS(n, i));
            float vx = cs * xv.x, vy = cs * xv.y;
            {
                const float2 u0 = *(const float2*)(&s.B[er0 + i]);
                const float2 u1 = *(const float2*)(&s.B[er1 + i]);
                const float2 u2 = *(const float2*)(&s.B[er2 + i]);
                const float2 u3 = *(const float2*)(&s.B[er3 + i]);
                vx += ec0 * u0.x + ec1 * u1.x + ec2 * u2.x + ec3 * u3.x;
                vy += ec0 * u0.y + ec1 * u1.y + ec2 * u2.y + ec3 * u3.y;
            }
            for (int j = e0 + 4; j < e1; ++j) {   // rare deg>4 remainder
                const int r = s.erow[j];
                const float c = s.dinv[r] * dn;
                const float2 u = *(const float2*)(&XS(r, i));
                vx += c * u.x; vy += c * u.y;
            }
            float2 o; o.x = vx; o.y = vy;
            *(float2*)(&XA(n, i)) = o;
        }
    }
    __syncthreads();

    // P5: h1 = relu(xa @ W1 + b1), 7 rows x 2 cols per thread
    if (t < 250) {
        const int fb = t % 25, nb = t / 25;
        const int f0 = fb * 2;
        float ax[7], ay[7];
        #pragma unroll
        for (int r = 0; r < 7; ++r) { ax[r] = 0.f; ay[r] = 0.f; }
        for (int i = 0; i < F0; i += 2) {
            const float2 wa = *(const float2*)(w1 + i * F1 + f0);
            const float2 wb = *(const float2*)(w1 + (i + 1) * F1 + f0);
            #pragma unroll
            for (int r = 0; r < 7; ++r) {
                const float2 xv = *(const float2*)(&XA(nb + 10 * r, i)); // in-struct even if n>=64
                ax[r] += xv.x * wa.x + xv.y * wb.x;
                ay[r] += xv.x * wa.y + xv.y * wb.y;
            }
        }
        const float bx = b1[f0], by = b1[f0 + 1];
        #pragma unroll
        for (int r = 0; r < 7; ++r) {
            const int n = nb + 10 * r;
            if (n < NPGC) {
                float2 o; o.x = fmaxf(ax[r] + bx, 0.f); o.y = fmaxf(ay[r] + by, 0.f);
                *(float2*)(&H1(n, f0)) = o;
            }
        }
    }
    __syncthreads();

    // P6: pool1 scores (4 lanes/row + shfl reduce)
    {
        const int n = t >> 2, q = t & 3;
        const int f0 = q * 13, len = (q == 3) ? 11 : 13;
        float a = 0.f, ss = 0.f;
        for (int j = 0; j < len; ++j) {
            const int f = f0 + j;
            const float w = pw1[f];
            ss += w * w;
            a += H1(n, f) * w;
        }
        a  += __shfl_xor(a, 1);  a  += __shfl_xor(a, 2);
        ss += __shfl_xor(ss, 1); ss += __shfl_xor(ss, 2);
        if (q == 0) s.score[n] = tanhf(a / sqrtf(ss));
    }
    __syncthreads();

    // P7: rank1 (stable descending == jax.lax.top_k) ; other threads zero counters
    if (t < NPGC) {
        const float sc = s.score[t]; int r = 0;
        for (int m = 0; m < NPGC; ++m) {
            const float sm = s.score[m];
            r += (sm > sc) || (sm == sc && m < t);
        }
        s.map[t] = (r < K1C) ? (signed char)r : (signed char)-1;
        if (r < K1C) s.inv[r] = (unsigned char)t;
    } else if (t < NPGC + 64) {
        s.cnt[t - NPGC] = 0;
    } else if (t < NPGC + 128) {
        s.ecnt[t - NPGC - 64] = 0;
    }
    __syncthreads();

    // P8: remap edges (u8 255 sentinel) + indegree2 via atomics
    if (t < EPGC) {
        const int mr = s.map[s.rowm[t]];
        const int mc = s.map[s.colm[t]];
        const bool keep = (mr >= 0) && (mc >= 0);
        s.rowm[t] = (unsigned char)(keep ? mr : 255);
        s.colm[t] = (unsigned char)(keep ? mc : 255);
        if (keep) atomicAdd(&s.cnt[mc], 1);
    }
    __syncthreads();

    // P9: dinv2 + scan
    if (t < K1C) {
        const int c = s.cnt[t];
        s.dinv[t] = rsqrtf(1.0f + (float)c);
        int sc_ = c;
        #pragma unroll
        for (int d = 1; d < 64; d <<= 1) {
            int y = __shfl_up(sc_, d, 64);
            if (t >= d) sc_ += y;
        }
        s.off[t + 1] = (unsigned short)sc_;
        if (t == 0) s.off[0] = 0;
    }
    __syncthreads();

    // P10: CSR2 fill (stores MAPPED src idx)
    if (t < EPGC) {
        const int c = s.colm[t];
        if (c != 255) {
            const int k = atomicAdd(&s.ecnt[c], 1);
            s.erow[s.off[c] + k] = s.rowm[t];
        }
    }
    __syncthreads();

    // P11: ha = N2.(h1[inv]*score)  (preloaded coefs; score folded in)
    if (t < 4 * K1C) {
        const int m = t >> 2, q = t & 3;
        const int i0 = q * 12;
        const int len = (q == 3) ? 14 : 12;
        const int e0 = s.off[m], e1 = s.off[m + 1];
        const int deg = e1 - e0;
        const float dn = s.dinv[m];
        const int ivn = s.inv[m];
        const float cs = dn * dn * s.score[ivn];
        const int rn = ivn * F1;
        int er0, er1, er2, er3; float ec0, ec1, ec2, ec3;
        {
            const int m0 = (0 < deg) ? s.erow[e0 + 0] : 0; const int v0 = s.inv[m0];
            const int m1 = (1 < deg) ? s.erow[e0 + 1] : 0; const int v1 = s.inv[m1];
            const int m2 = (2 < deg) ? s.erow[e0 + 2] : 0; const int v2 = s.inv[m2];
            const int m3 = (3 < deg) ? s.erow[e0 + 3] : 0; const int v3 = s.inv[m3];
            er0 = v0 * F1; ec0 = (0 < deg) ? s.dinv[m0] * dn * s.score[v0] : 0.f;
            er1 = v1 * F1; ec1 = (1 < deg) ? s.dinv[m1] * dn * s.score[v1] : 0.f;
            er2 = v2 * F1; ec2 = (2 < deg) ? s.dinv[m2] * dn * s.score[v2] : 0.f;
            er3 = v3 * F1; ec3 = (3 < deg) ? s.dinv[m3] * dn * s.score[v3] : 0.f;
        }
        for (int ii = 0; ii < len; ii += 2) {
            const int i = i0 + ii;
            const float2 hv = *(const float2*)(&s.A[rn + i]);
            float vx = cs * hv.x, vy = cs * hv.y;
            {
                const float2 u0 = *(const float2*)(&s.A[er0 + i]);
                const float2 u1 = *(const float2*)(&s.A[er1 + i]);
                const float2 u2 = *(const float2*)(&s.A[er2 + i]);
                const float2 u3 = *(const float2*)(&s.A[er3 + i]);
                vx += ec0 * u0.x + ec1 * u1.x + ec2 * u2.x + ec3 * u3.x;
                vy += ec0 * u0.y + ec1 * u1.y + ec2 * u2.y + ec3 * u3.y;
            }
            for (int j = e0 + 4; j < e1; ++j) {
                const int mr = s.erow[j];
                const int ivr = s.inv[mr];
                const float c = s.dinv[mr] * dn * s.score[ivr];
                const float2 u = *(const float2*)(&s.A[ivr * F1 + i]);
                vx += c * u.x; vy += c * u.y;
            }
            float2 o; o.x = vx; o.y = vy;
            *(float2*)(&HA(m, i)) = o;
        }
    }
    __syncthreads();

    // P12: h2 = relu(ha @ W2 + b2), 6 rows x 4 cols per thread (overwrites h1 region)
    if (t < 250) {
        const int fb = t % 25, nb = t / 25;
        const int f0 = fb * 4;
        float4 acc[6];
        #pragma unroll
        for (int r = 0; r < 6; ++r) { acc[r].x = 0.f; acc[r].y = 0.f; acc[r].z = 0.f; acc[r].w = 0.f; }
        for (int i = 0; i < F1; i += 2) {
            const float4 wa = *(const float4*)(w2 + i * F2 + f0);
            const float4 wb = *(const float4*)(w2 + (i + 1) * F2 + f0);
            #pragma unroll
            for (int r = 0; r < 6; ++r) {
                const float2 hv = *(const float2*)(&HA(nb + 10 * r, i)); // in-struct even if m>=52
                acc[r].x += hv.x * wa.x + hv.y * wb.x;
                acc[r].y += hv.x * wa.y + hv.y * wb.y;
                acc[r].z += hv.x * wa.z + hv.y * wb.z;
                acc[r].w += hv.x * wa.w + hv.y * wb.w;
            }
        }
        const float4 bb = *(const float4*)(cb2 + f0);
        #pragma unroll
        for (int r = 0; r < 6; ++r) {
            const int m = nb + 10 * r;
            if (m < K1C) {
                float4 o;
                o.x = fmaxf(acc[r].x + bb.x, 0.f);
                o.y = fmaxf(acc[r].y + bb.y, 0.f);
                o.z = fmaxf(acc[r].z + bb.z, 0.f);
                o.w = fmaxf(acc[r].w + bb.w, 0.f);
                *(float4*)(&H2(m, f0)) = o;
            }
        }
    }
    __syncthreads();

    // P13: pool2 scores (pure h2 reads)
    if (t < 4 * K1C) {
        const int m = t >> 2, q = t & 3;
        const int f0 = q * 25;
        float a = 0.f, ss = 0.f;
        for (int j = 0; j < 25; ++j) {
            const int f = f0 + j;
            const float w = pw2[f];
            ss += w * w;
            a += H2(m, f) * w;
        }
        a  += __shfl_xor(a, 1);  a  += __shfl_xor(a, 2);
        ss += __shfl_xor(ss, 1); ss += __shfl_xor(ss, 2);
        if (q == 0) s.score2[m] = tanhf(a / sqrtf(ss));
    }
    __syncthreads();

    // P14: rank2
    if (t < K1C) {
        const float sc = s.score2[t]; int r = 0;
        for (int m = 0; m < K1C; ++m) {
            const float sm = s.score2[m];
            r += (sm > sc) || (sm == sc && m < t);
        }
        if (r < K2C) s.inv2[r] = (unsigned char)t;
    }
    __syncthreads();

    // P15: readout partials (two row-halves x 100 feats)
    if (t < 200) {
        const int f = t % 100, hh = t / 100;
        float mx = -INFINITY, sm = 0.f;
        for (int r = hh * 21; r < hh * 21 + 21; ++r) {
            const int n = s.inv2[r];
            const float y = H2(n, f) * s.score2[n];
            mx = fmaxf(mx, y);
            sm += y;
        }
        RD(hh * 100 + f)       = mx;
        RD(200 + hh * 100 + f) = sm;
    }
    __syncthreads();

    // P16: combine + write pooled
    if (t < F2) {
        float* pd = ws_pooled + (size_t)g * 200;
        pd[t]       = fmaxf(RD(t), RD(100 + t));
        pd[100 + t] = (RD(200 + t) + RD(300 + t)) * (1.0f / (float)K2C);
    }
}

// ---------------- head kernel: 8 graphs/block (round-6 proven config) ----------------
#define GPB 8
struct HS {
    union {
        float sp[GPB * 201];
        struct { float d1[GPB * 100]; float d2[GPB * 201]; } b;
    } u;
    float le[GPB * 201];
    float muv[GPB * 50];
    int   sls[GPB];
};

__global__ __launch_bounds__(TPB, 4)
void molgen_head(const float* __restrict__ ws_pooled,
                 const int* __restrict__ smile_len,
                 const float* __restrict__ emb,
                 const float* __restrict__ mean_w,   const float* __restrict__ mean_b,
                 const float* __restrict__ logvar_w, const float* __restrict__ logvar_b,
                 const float* __restrict__ dec1_w, const float* __restrict__ dec1_b,
                 const float* __restrict__ dec2_w, const float* __restrict__ dec2_b,
                 const float* __restrict__ out_w,  const float* __restrict__ out_b,
                 float* __restrict__ out, int B)
{
    __shared__ HS h;
    const int t  = threadIdx.x;
    const int g0 = blockIdx.x * GPB;

    if (t < GPB) h.sls[t] = (g0 + t < B) ? smile_len[g0 + t] : 0;
    __syncthreads();
    for (int o = t; o < GPB * 200; o += TPB) {
        const int gg = o / 200, f = o - gg * 200;
        if (g0 + gg < B) {
            h.u.sp[gg * 201 + f] = ws_pooled[(size_t)(g0 + gg) * 200 + f];
            h.le[gg * 201 + f]   = fmaxf(emb[(size_t)h.sls[gg] * 200 + f], 0.f);
        }
    }
    __syncthreads();

    // mu & logvar: j = t%50, 2 graphs per thread
    if (t < 200) {
        const int j = t % 50, gq = t / 50;
        float am[2] = {mean_b[j], mean_b[j]};
        float al[2] = {logvar_b[j], logvar_b[j]};
        for (int i = 0; i < 200; ++i) {
            const float wm = mean_w[i * 50 + j];
            const float wl = logvar_w[i * 50 + j];
            #pragma unroll
            for (int k = 0; k < 2; ++k) {
                const float p = h.u.sp[(gq * 2 + k) * 201 + i];
                am[k] += p * wm;
                al[k] += p * wl;
            }
        }
        #pragma unroll
        for (int k = 0; k < 2; ++k) {
            const int gg = gq * 2 + k;
            if (g0 + gg < B) {
                const float m = fmaxf(am[k], 0.f);
                h.muv[gg * 50 + j] = m;
                out[(size_t)B * 200 + (size_t)(g0 + gg) * 50 + j] = m;
                out[(size_t)B * 250 + (size_t)(g0 + gg) * 50 + j] = fmaxf(al[k], 0.f);
            }
        }
    }
    __syncthreads();   // sp dead; d1 aliases it

    // d1 = relu([mu, lemb] @ dec1_w + b): j = t%100, 4 graphs per thread
    if (t < 200) {
        const int j = t % 100, gh = t / 100;
        float a[4];
        #pragma unroll
        for (int k = 0; k < 4; ++k) a[k] = dec1_b[j];
        for (int i = 0; i < 50; ++i) {
            const float w = dec1_w[i * 100 + j];
            #pragma unroll
            for (int k = 0; k < 4; ++k) a[k] += h.muv[(gh * 4 + k) * 50 + i] * w;
        }
        for (int i = 0; i < 200; ++i) {
            const float w = dec1_w[(50 + i) * 100 + j];
            #pragma unroll
            for (int k = 0; k < 4; ++k) a[k] += h.le[(gh * 4 + k) * 201 + i] * w;
        }
        #pragma unroll
        for (int k = 0; k < 4; ++k) h.u.b.d1[(gh * 4 + k) * 100 + j] = fmaxf(a[k], 0.f);
    }
    __syncthreads();

    // d2 = relu(d1 @ dec2_w + b) + lemb: j = t, all 8 graphs
    if (t < 200) {
        const int j = t;
        float a[GPB];
        #pragma unroll
        for (int k = 0; k < GPB; ++k) a[k] = dec2_b[j];
        for (int i = 0; i < 100; ++i) {
            const float w = dec2_w[i * 200 + j];
            #pragma unroll
            for (int k = 0; k < GPB; ++k) a[k] += h.u.b.d1[k * 100 + i] * w;
        }
        #pragma unroll
        for (int k = 0; k < GPB; ++k)
            h.u.b.d2[k * 201 + j] = fmaxf(a[k], 0.f) + h.le[k * 201 + j];
    }
    __syncthreads();

    // out = relu(d2 @ out_w + b)
    if (t < 200) {
        const int j = t;
        float a[GPB];
        #pragma unroll
        for (int k = 0; k < GPB; ++k) a[k] = out_b[j];
        for (int i = 0; i < 200; ++i) {
            const float w = out_w[i * 200 + j];
            #pragma unroll
            for (int k = 0; k < GPB; ++k) a[k] += h.u.b.d2[k * 201 + i] * w;
        }
        #pragma unroll
        for (int k = 0; k < GPB; ++k)
            if (g0 + k < B) out[(size_t)(g0 + k) * 200 + j] = fmaxf(a[k], 0.f);
    }
}

extern "C" void kernel_launch(void* const* d_in, const int* in_sizes, int n_in,
                              void* d_out, int out_size, void* d_ws, size_t ws_size,
                              hipStream_t stream) {
    const float* x        = (const float*)d_in[0];
    const int*   ei       = (const int*)d_in[1];
    const int*   slen     = (const int*)d_in[3];
    const float* w1       = (const float*)d_in[4];
    const float* b1       = (const float*)d_in[5];
    const float* pw1      = (const float*)d_in[6];
    const float* w2       = (const float*)d_in[7];
    const float* b2       = (const float*)d_in[8];
    const float* pw2      = (const float*)d_in[9];
    const float* mean_w   = (const float*)d_in[10];
    const float* mean_b   = (const float*)d_in[11];
    const float* logvar_w = (const float*)d_in[12];
    const float* logvar_b = (const float*)d_in[13];
    const float* emb      = (const float*)d_in[14];
    const float* dec1_w   = (const float*)d_in[15];
    const float* dec1_b   = (const float*)d_in[16];
    const float* dec2_w   = (const float*)d_in[17];
    const float* dec2_b   = (const float*)d_in[18];
    const float* out_w    = (const float*)d_in[19];
    const float* out_b    = (const float*)d_in[20];

    const int B = in_sizes[3];
    const int E = in_sizes[1] / 2;

    float* pooled = (float*)d_ws;   // [B][200] fp32

    molgen_graph<<<B, TPB, 0, stream>>>(x, ei, w1, b1, pw1, w2, b2, pw2, pooled, E);
    molgen_head<<<(B + GPB - 1) / GPB, TPB, 0, stream>>>(pooled, slen, emb,
        mean_w, mean_b, logvar_w, logvar_b, dec1_w, dec1_b, dec2_w, dec2_b,
        out_w, out_b, (float*)d_out, B);
}